// Round 3
// baseline (304.268 us; speedup 1.0000x reference)
//
#include <hip/hip_runtime.h>

typedef short short8 __attribute__((ext_vector_type(8)));
typedef short short4v __attribute__((ext_vector_type(4)));
typedef float floatx4 __attribute__((ext_vector_type(4)));

#define BB 4
#define CC 124
#define CP 128
#define NN 4096
#define NSPLIT 8
#define KSPLIT (NN / NSPLIT)   // 512 keys per split
#define TN 64                  // keys per chunk
#define NCHUNK (KSPLIT / TN)   // 8

static __device__ __forceinline__ unsigned short f2bf(float f) {
    unsigned int u = __float_as_uint(f);
    u += 0x7fffu + ((u >> 16) & 1u);
    return (unsigned short)(u >> 16);
}
static __device__ __forceinline__ float bf2f(unsigned short u) {
    return __uint_as_float(((unsigned int)u) << 16);
}

// ---------------------------------------------------------------------------
// Bf[b,o,n] = sum_c Wb[o,c] * x[b,c,n] in bf16, two layouts:
//   rows[b][n][CP] (Q/K frags), cols[b][CP][NN] (V frags); pad c 124..127 = 0.
// Also m2[b][n] = log2(e)*||Bf[:,n]||^2, the fixed softmax stabilizer (the
// diagonal is the row max with ~80 margin in exp2 space; any per-row constant
// is exact for softmax as long as exp2 doesn't overflow).
// ---------------------------------------------------------------------------
__global__ __launch_bounds__(256) void bf_proj_kernel(const float* __restrict__ x,
                                                      const float* __restrict__ Wb,
                                                      unsigned short* __restrict__ rows,
                                                      unsigned short* __restrict__ cols,
                                                      float* __restrict__ m2) {
    __shared__ float xs[CC][68];
    __shared__ float wsh[CP][CC];
    __shared__ unsigned short ts[64][CP];
    __shared__ float msh[16][64];
    const int tid = threadIdx.x;
    const int b = blockIdx.y;
    const int n0 = blockIdx.x * 64;
    const float* xb = x + (size_t)b * CC * NN + n0;
    for (int i = tid; i < CC * 64; i += 256) {
        int c = i >> 6, n = i & 63;
        xs[c][n] = xb[(size_t)c * NN + n];
    }
    for (int i = tid; i < CC * CC; i += 256) wsh[i / CC][i % CC] = Wb[i];
    for (int i = tid; i < 4 * CC; i += 256) wsh[CC + i / CC][i % CC] = 0.0f;
    __syncthreads();
    const int og = tid >> 4;
    const int n4 = (tid & 15) * 4;
    const int o0 = og * 8;
    float acc[8][4];
#pragma unroll
    for (int k = 0; k < 8; ++k)
#pragma unroll
        for (int j = 0; j < 4; ++j) acc[k][j] = 0.f;
    for (int c = 0; c < CC; ++c) {
        floatx4 xv = *(const floatx4*)&xs[c][n4];
#pragma unroll
        for (int k = 0; k < 8; ++k) {
            float wv = wsh[o0 + k][c];
            acc[k][0] += wv * xv[0];
            acc[k][1] += wv * xv[1];
            acc[k][2] += wv * xv[2];
            acc[k][3] += wv * xv[3];
        }
    }
    unsigned short* colb = cols + (size_t)b * CP * NN + n0;
    float sq[4] = {0.f, 0.f, 0.f, 0.f};
#pragma unroll
    for (int k = 0; k < 8; ++k) {
#pragma unroll
        for (int j = 0; j < 4; ++j) {
            float a = acc[k][j];
            sq[j] += a * a;
            unsigned short v = f2bf(a);
            ts[n4 + j][o0 + k] = v;
            colb[(size_t)(o0 + k) * NN + n4 + j] = v;
        }
    }
#pragma unroll
    for (int j = 0; j < 4; ++j) msh[og][n4 + j] = sq[j];
    __syncthreads();
    unsigned short* rowb = rows + ((size_t)b * NN + n0) * CP;
    const unsigned short* tsf = &ts[0][0];
    for (int i = tid; i < (64 * CP) / 4; i += 256)
        ((short4v*)rowb)[i] = ((const short4v*)tsf)[i];
    if (tid < 64) {
        float s = 0.f;
#pragma unroll
        for (int og2 = 0; og2 < 16; ++og2) s += msh[og2][tid];
        m2[(size_t)b * NN + n0 + tid] = s * 1.44269504088896340736f;
    }
}

// ---------------------------------------------------------------------------
// Flash attention, ZERO LDS, no cross-lane ops in the hot loop.
// Trick: QK computed operand-swapped -> S^T in C-layout, whose per-lane data
// IS the A-fragment of P for mfma_f32_16x16x16bf16_1k (A[m=lane&15][k=quad*4+j]).
// So P goes registers->MFMA directly; lsum is a per-lane scalar (m = col).
// ---------------------------------------------------------------------------
__global__ __launch_bounds__(256, 3) void attn_kernel(const unsigned short* __restrict__ rows,
                                                      const unsigned short* __restrict__ cols,
                                                      const float* __restrict__ m2,
                                                      unsigned short* __restrict__ opart,
                                                      float* __restrict__ ml) {
    // XCD x (= id%8) serves split x across all 4 batches: ~1MB L2 key stream.
    const int id = blockIdx.x;
    const int ghi = id & 7;
    const int r_ = id >> 3;
    const int glo = r_ >> 5;
    const int mtile = r_ & 31;
    const int grp = ghi * 4 + glo;   // 0..31
    const int b = grp & 3;
    const int split = grp >> 2;      // 0..7
    const int wave = threadIdx.x >> 6;
    const int lane = threadIdx.x & 63;
    const int col = lane & 15;
    const int quad = lane >> 4;
    const int m0 = mtile * 128 + wave * 32;
    const unsigned short* rb = rows + (size_t)b * NN * CP;
    const unsigned short* cb = cols + (size_t)b * CP * NN;
    const floatx4 fzero = {0.f, 0.f, 0.f, 0.f};
    const float L2E = 1.44269504088896340736f;

    // Q frags resident in registers (used as B operand of the swapped QK)
    short8 qf[2][4];
#pragma unroll
    for (int ms = 0; ms < 2; ++ms) {
        const unsigned short* qrow = rb + (size_t)(m0 + ms * 16 + col) * CP + quad * 8;
#pragma unroll
        for (int t = 0; t < 4; ++t) qf[ms][t] = *(const short8*)(qrow + t * 32);
    }
    // per-lane stabilizer: this lane's query row is m = m0 + ms*16 + col
    float mreg[2];
    mreg[0] = m2[(size_t)b * NN + m0 + col];
    mreg[1] = m2[(size_t)b * NN + m0 + 16 + col];

    floatx4 oacc[2][8];
#pragma unroll
    for (int ms = 0; ms < 2; ++ms)
#pragma unroll
        for (int s8 = 0; s8 < 8; ++s8) oacc[ms][s8] = fzero;
    float lsum[2] = {0.f, 0.f};

    for (int ch = 0; ch < NCHUNK; ++ch) {
        const int n0 = split * KSPLIT + ch * TN;
        // ---- S^T = K Q^T over this 64-key chunk (operand-swapped) ----
        floatx4 st[2][4];
#pragma unroll
        for (int ms = 0; ms < 2; ++ms)
#pragma unroll
            for (int u = 0; u < 4; ++u) st[ms][u] = fzero;
#pragma unroll
        for (int t = 0; t < 4; ++t) {
#pragma unroll
            for (int u = 0; u < 4; ++u) {
                short8 kf = *(const short8*)(rb + (size_t)(n0 + u * 16 + col) * CP + t * 32 + quad * 8);
                st[0][u] = __builtin_amdgcn_mfma_f32_16x16x32_bf16(kf, qf[0][t], st[0][u], 0, 0, 0);
                st[1][u] = __builtin_amdgcn_mfma_f32_16x16x32_bf16(kf, qf[1][t], st[1][u], 0, 0, 0);
            }
        }
        // ---- softmax numerator, packed straight into PV A-frags ----
        short4v af[2][4];
#pragma unroll
        for (int ms = 0; ms < 2; ++ms) {
#pragma unroll
            for (int u = 0; u < 4; ++u) {
                float ps = 0.f;
#pragma unroll
                for (int r = 0; r < 4; ++r) {
                    float p = exp2f(__builtin_fmaf(st[ms][u][r], L2E, -mreg[ms]));
                    af[ms][u][r] = (short)f2bf(p);
                    ps += p;
                }
                lsum[ms] += ps;
            }
        }
        // ---- O += P V  (K=16 MFMAs; P already in A-layout) ----
#pragma unroll
        for (int u = 0; u < 4; ++u) {
#pragma unroll
            for (int s8 = 0; s8 < 8; ++s8) {
                short4v vf = *(const short4v*)(cb + (size_t)(s8 * 16 + col) * NN + n0 + u * 16 + quad * 4);
                oacc[0][s8] = __builtin_amdgcn_mfma_f32_16x16x16bf16_1k(af[0][u], vf, oacc[0][s8], 0, 0, 0);
                oacc[1][s8] = __builtin_amdgcn_mfma_f32_16x16x16bf16_1k(af[1][u], vf, oacc[1][s8], 0, 0, 0);
            }
        }
    }
    // ---- epilogue: bf16 unnormalized partials + per-row partial l ----
    unsigned short* ob = opart + (size_t)(split * BB + b) * NN * CP;
#pragma unroll
    for (int ms = 0; ms < 2; ++ms)
#pragma unroll
        for (int s8 = 0; s8 < 8; ++s8)
#pragma unroll
            for (int r = 0; r < 4; ++r)
                ob[(size_t)(m0 + ms * 16 + quad * 4 + r) * CP + s8 * 16 + col] = f2bf(oacc[ms][s8][r]);
#pragma unroll
    for (int ms = 0; ms < 2; ++ms) {
        float v = lsum[ms];
        v += __shfl_xor(v, 16);
        v += __shfl_xor(v, 32);
        if (lane < 16)
            ml[(size_t)(split * BB + b) * NN + m0 + ms * 16 + lane] = v;
    }
}

// ---------------------------------------------------------------------------
// Linear combine of the 8 split partials + normalize + gamma*E + x.
// 512 blocks (32 m-rows each) for occupancy; 32 independent 8B loads/thread;
// LDS transpose so [b][c][m] writes are contiguous.
// ---------------------------------------------------------------------------
__global__ __launch_bounds__(256) void combine_kernel(const unsigned short* __restrict__ opart,
                                                      const float* __restrict__ ml,
                                                      const float* __restrict__ x,
                                                      const float* __restrict__ gamma,
                                                      float* __restrict__ out) {
    __shared__ float es[32 * 133];
    __shared__ float Lsh[32];
    const int t = threadIdx.x;
    const int b = blockIdx.y;
    const int m0 = blockIdx.x * 32;
    if (t < 32) {
        float L = 0.f;
#pragma unroll
        for (int s = 0; s < NSPLIT; ++s) L += ml[(size_t)(s * BB + b) * NN + m0 + t];
        Lsh[t] = gamma[0] / L;
    }
    const int tc = t & 31, tm = t >> 5;   // tm 0..7 -> 4 m-rows each; tc -> 4 channels
    float acc[4][4];
#pragma unroll
    for (int i = 0; i < 4; ++i)
#pragma unroll
        for (int j = 0; j < 4; ++j) acc[i][j] = 0.f;
    for (int s = 0; s < NSPLIT; ++s) {
        const unsigned short* obp = opart + ((size_t)(s * BB + b) * NN + m0 + tm * 4) * CP + tc * 4;
#pragma unroll
        for (int i = 0; i < 4; ++i) {
            short4v v = *(const short4v*)(obp + (size_t)i * CP);
            acc[i][0] += bf2f((unsigned short)v[0]);
            acc[i][1] += bf2f((unsigned short)v[1]);
            acc[i][2] += bf2f((unsigned short)v[2]);
            acc[i][3] += bf2f((unsigned short)v[3]);
        }
    }
#pragma unroll
    for (int i = 0; i < 4; ++i)
#pragma unroll
        for (int j = 0; j < 4; ++j) es[(tm * 4 + i) * 133 + tc * 4 + j] = acc[i][j];
    __syncthreads();
    const int wave = t >> 6, lane = t & 63;
    const int half = lane >> 5, lm = lane & 31;
#pragma unroll
    for (int p = 0; p < 16; ++p) {
        int c = p * 8 + wave * 2 + half;
        if (c < CC) {
            size_t base = ((size_t)b * CC + c) * NN + m0 + lm;
            out[base] = es[lm * 133 + c] * Lsh[lm] + x[base];
        }
    }
}

extern "C" void kernel_launch(void* const* d_in, const int* in_sizes, int n_in,
                              void* d_out, int out_size, void* d_ws, size_t ws_size,
                              hipStream_t stream) {
    const float* x = (const float*)d_in[0];
    const float* Wb = (const float*)d_in[1];
    const float* gamma = (const float*)d_in[2];
    float* out = (float*)d_out;

    const size_t rows_b = (size_t)BB * NN * CP * sizeof(unsigned short);       // 4 MB
    const size_t cols_b = rows_b;                                              // 4 MB
    const size_t m2_b = (size_t)BB * NN * sizeof(float);                       // 64 KB
    const size_t ml_b = (size_t)NSPLIT * BB * NN * sizeof(float);              // 512 KB
    const size_t opart_b = (size_t)NSPLIT * BB * NN * CP * sizeof(unsigned short); // 32 MB
    if (ws_size < rows_b + cols_b + m2_b + ml_b + opart_b) return;

    char* w = (char*)d_ws;
    unsigned short* rows = (unsigned short*)w;
    unsigned short* cols = (unsigned short*)(w + rows_b);
    float* m2 = (float*)(w + rows_b + cols_b);
    float* ml = (float*)(w + rows_b + cols_b + m2_b);
    unsigned short* opart = (unsigned short*)(w + rows_b + cols_b + m2_b + ml_b);

    bf_proj_kernel<<<dim3(NN / 64, BB), 256, 0, stream>>>(x, Wb, rows, cols, m2);
    attn_kernel<<<dim3(1024), 256, 0, stream>>>(rows, cols, m2, opart, ml);
    combine_kernel<<<dim3(NN / 32, BB), 256, 0, stream>>>(opart, ml, x, gamma, out);
}

// Round 4
// 134.935 us; speedup vs baseline: 2.2549x; 2.2549x over previous
//
#include <hip/hip_runtime.h>

typedef short short8 __attribute__((ext_vector_type(8)));
typedef short short4v __attribute__((ext_vector_type(4)));
typedef float floatx4 __attribute__((ext_vector_type(4)));

#define BB 4
#define CC 124
#define CP 128
#define NN 4096
#define NGRP 256               // 16-key groups per batch
#define NSPLIT 4
#define KSPLIT (NN / NSPLIT)   // 1024 keys per split
#define TN 64                  // keys per chunk
#define NCHUNK (KSPLIT / TN)   // 16

static __device__ __forceinline__ unsigned short f2bf(float f) {
    unsigned int u = __float_as_uint(f);
    u += 0x7fffu + ((u >> 16) & 1u);
    return (unsigned short)(u >> 16);
}
static __device__ __forceinline__ float bf2f(unsigned short u) {
    return __uint_as_float(((unsigned int)u) << 16);
}

// async global->LDS, 16B per lane; LDS dest = wave-uniform base + lane*16
static __device__ __forceinline__ void gl16(const unsigned short* g, unsigned short* l) {
    __builtin_amdgcn_global_load_lds(
        (const __attribute__((address_space(1))) unsigned int*)g,
        (__attribute__((address_space(3))) unsigned int*)l, 16, 0, 0);
}

// ---------------------------------------------------------------------------
// Projection Bf = Wb x, written DIRECTLY in MFMA-fragment order (bf16):
//  kfrag[b][g][t][lane]*8  : 16B unit = Bf[n=g*16+(lane&15)][c=t*32+(lane>>4)*8 ..+8]
//    (serves both K A-frags and Q B-frags of the operand-swapped QK)
//  vfrag[b][g][s8][lane]*4 :  8B unit = Bf[c=s8*16+(lane&15)][n=g*16+(lane>>4)*4 ..+4]
//    (V B-frags for the K=16 PV MFMA)
// Plus m2[b][n] = log2(e)*||Bf[:,n]||^2 (fixed softmax stabilizer; the diagonal
// is the row max with ~80 margin in exp2 space, so no online max needed).
// ---------------------------------------------------------------------------
__global__ __launch_bounds__(256) void bf_proj_kernel(const float* __restrict__ x,
                                                      const float* __restrict__ Wb,
                                                      unsigned short* __restrict__ kfrag,
                                                      unsigned short* __restrict__ vfrag,
                                                      float* __restrict__ m2) {
    __shared__ float xs[CC][68];
    __shared__ float wsh[CP][CC];
    __shared__ float msh[16][64];
    const int tid = threadIdx.x;
    const int b = blockIdx.y;
    const int n0 = blockIdx.x * 64;
    const float* xb = x + (size_t)b * CC * NN + n0;
    for (int i = tid; i < CC * 64; i += 256) {
        int c = i >> 6, n = i & 63;
        xs[c][n] = xb[(size_t)c * NN + n];
    }
    for (int i = tid; i < CC * CC; i += 256) wsh[i / CC][i % CC] = Wb[i];
    for (int i = tid; i < 4 * CC; i += 256) wsh[CC + i / CC][i % CC] = 0.0f;
    __syncthreads();
    const int og = tid >> 4;         // o0 = og*8
    const int n4 = (tid & 15) * 4;   // n-offset within 64-tile
    const int o0 = og * 8;
    float acc[8][4];
#pragma unroll
    for (int k = 0; k < 8; ++k)
#pragma unroll
        for (int j = 0; j < 4; ++j) acc[k][j] = 0.f;
    for (int c = 0; c < CC; ++c) {
        floatx4 xv = *(const floatx4*)&xs[c][n4];
#pragma unroll
        for (int k = 0; k < 8; ++k) {
            float wv = wsh[o0 + k][c];
            acc[k][0] += wv * xv[0];
            acc[k][1] += wv * xv[1];
            acc[k][2] += wv * xv[2];
            acc[k][3] += wv * xv[3];
        }
    }
    // ---- stats ----
    float sq[4] = {0.f, 0.f, 0.f, 0.f};
#pragma unroll
    for (int k = 0; k < 8; ++k)
#pragma unroll
        for (int j = 0; j < 4; ++j) sq[j] += acc[k][j] * acc[k][j];
#pragma unroll
    for (int j = 0; j < 4; ++j) msh[og][n4 + j] = sq[j];
    // ---- kfrag: per j one 16B unit (8 c-values) ----
    const int g = (n0 >> 4) + ((tid >> 2) & 3);   // (n0 + n4)/16
    const int colk = n4 & 15;                     // key col base (j adds 0..3)
    const int tK = o0 >> 5;
    const int qK = (o0 >> 3) & 3;
#pragma unroll
    for (int j = 0; j < 4; ++j) {
        short8 kv;
#pragma unroll
        for (int k = 0; k < 8; ++k) kv[k] = (short)f2bf(acc[k][j]);
        *(short8*)&kfrag[(((size_t)(b * NGRP + g) * 4 + tK) * 64 + qK * 16 + colk + j) * 8] = kv;
    }
    // ---- vfrag: per k one 8B unit (4 n-values) ----
    const int s8v = o0 >> 4;
    const int qv = tid & 3;                       // (n%16)/4
    const int colv0 = (og & 1) * 8;
#pragma unroll
    for (int k = 0; k < 8; ++k) {
        short4v vv;
#pragma unroll
        for (int j = 0; j < 4; ++j) vv[j] = (short)f2bf(acc[k][j]);
        *(short4v*)&vfrag[(((size_t)(b * NGRP + g) * 8 + s8v) * 64 + qv * 16 + colv0 + k) * 4] = vv;
    }
    __syncthreads();
    if (tid < 64) {
        float s = 0.f;
#pragma unroll
        for (int og2 = 0; og2 < 16; ++og2) s += msh[og2][tid];
        m2[(size_t)b * NN + n0 + tid] = s * 1.44269504088896340736f;
    }
}

// ---------------------------------------------------------------------------
// Flash attention, m97-style: async global_load_lds staging of pre-fragmented
// K/V tiles, double-buffered, ONE barrier per chunk; fragment reads are
// canonical conflict-free ds_read_b128/b64. Operand-swapped QK keeps P in
// registers (A-layout of the K=16 PV MFMA); per-lane lsum (query m = lane&15).
// ---------------------------------------------------------------------------
__global__ __launch_bounds__(256, 2) void attn_kernel(const unsigned short* __restrict__ kfrag,
                                                      const unsigned short* __restrict__ vfrag,
                                                      const float* __restrict__ m2,
                                                      unsigned short* __restrict__ opart,
                                                      float* __restrict__ ml) {
    __shared__ unsigned short kbuf[2][16 * 64 * 8];   // 16 KB per buffer
    __shared__ unsigned short vbuf[2][32 * 64 * 4];   // 16 KB per buffer
    // XCD x (= id%8) serves grps {2x, 2x+1}: ~1 MB L2-resident stream per XCD
    const int id = blockIdx.x;
    const int ghi = id & 7;
    const int r_ = id >> 3;
    const int mtile = r_ & 31;
    const int glo = r_ >> 5;          // 0..1
    const int grp = ghi * 2 + glo;    // 0..15
    const int b = grp & 3;
    const int split = grp >> 2;       // 0..3
    const int w = threadIdx.x >> 6;
    const int lane = threadIdx.x & 63;
    const int col = lane & 15;
    const int m0 = mtile * 128 + w * 32;
    const int g0 = split * (KSPLIT / 16);  // first 16-key group of this split
    const floatx4 fzero = {0.f, 0.f, 0.f, 0.f};
    const float L2E = 1.44269504088896340736f;

    // Q frags (B operand of swapped QK), resident in registers
    short8 qf[2][4];
#pragma unroll
    for (int ms = 0; ms < 2; ++ms) {
        const int gq = (m0 >> 4) + ms;
#pragma unroll
        for (int t = 0; t < 4; ++t)
            qf[ms][t] = *(const short8*)&kfrag[(((size_t)(b * NGRP + gq) * 4 + t) * 64 + lane) * 8];
    }
    float mreg[2];
    mreg[0] = m2[(size_t)b * NN + m0 + col];
    mreg[1] = m2[(size_t)b * NN + m0 + 16 + col];

    floatx4 oacc[2][8];
#pragma unroll
    for (int ms = 0; ms < 2; ++ms)
#pragma unroll
        for (int s8 = 0; s8 < 8; ++s8) oacc[ms][s8] = fzero;
    float lsum[2] = {0.f, 0.f};

    // wave w stages key-group g0 + ch*4 + w each chunk (4 KB K + 4 KB V)
    auto stage = [&](int ch, int sel) {
        const size_t gg = (size_t)(b * NGRP + g0 + ch * 4 + w);
        const unsigned short* kg = kfrag + gg * 4 * 64 * 8;
        unsigned short* kl = &kbuf[sel][w * 4 * 64 * 8];
#pragma unroll
        for (int t = 0; t < 4; ++t)
            gl16(kg + (size_t)(t * 64 + lane) * 8, kl + t * 64 * 8);
        const unsigned short* vg = vfrag + gg * 8 * 64 * 4;
        unsigned short* vl = &vbuf[sel][w * 8 * 64 * 4];
#pragma unroll
        for (int p = 0; p < 4; ++p)
            gl16(vg + (size_t)(p * 512) + lane * 8, vl + p * 512);
    };

    stage(0, 0);
#pragma unroll 2
    for (int ch = 0; ch < NCHUNK; ++ch) {
        const int sel = ch & 1;
        __syncthreads();                       // drains staging DMA + guards buffer reuse
        if (ch + 1 < NCHUNK) stage(ch + 1, sel ^ 1);
        // ---- S^T = K Q^T over 64 keys (operand-swapped) ----
        floatx4 st[2][4];
#pragma unroll
        for (int ms = 0; ms < 2; ++ms)
#pragma unroll
            for (int u = 0; u < 4; ++u) st[ms][u] = fzero;
#pragma unroll
        for (int t = 0; t < 4; ++t) {
#pragma unroll
            for (int u = 0; u < 4; ++u) {
                short8 kf = *(const short8*)&kbuf[sel][((u * 4 + t) * 64 + lane) * 8];
                st[0][u] = __builtin_amdgcn_mfma_f32_16x16x32_bf16(kf, qf[0][t], st[0][u], 0, 0, 0);
                st[1][u] = __builtin_amdgcn_mfma_f32_16x16x32_bf16(kf, qf[1][t], st[1][u], 0, 0, 0);
            }
        }
        // ---- softmax numerator -> PV A-frags (registers only) ----
        short4v af[2][4];
#pragma unroll
        for (int ms = 0; ms < 2; ++ms) {
#pragma unroll
            for (int u = 0; u < 4; ++u) {
                float ps = 0.f;
#pragma unroll
                for (int r = 0; r < 4; ++r) {
                    float p = exp2f(__builtin_fmaf(st[ms][u][r], L2E, -mreg[ms]));
                    af[ms][u][r] = (short)f2bf(p);
                    ps += p;
                }
                lsum[ms] += ps;
            }
        }
        // ---- O += P V ----
#pragma unroll
        for (int u = 0; u < 4; ++u) {
#pragma unroll
            for (int s8 = 0; s8 < 8; ++s8) {
                short4v vf = *(const short4v*)&vbuf[sel][((u * 8 + s8) * 64 + lane) * 4];
                oacc[0][s8] = __builtin_amdgcn_mfma_f32_16x16x16bf16_1k(af[0][u], vf, oacc[0][s8], 0, 0, 0);
                oacc[1][s8] = __builtin_amdgcn_mfma_f32_16x16x16bf16_1k(af[1][u], vf, oacc[1][s8], 0, 0, 0);
            }
        }
    }
    // ---- epilogue: bf16 unnormalized partials + per-row partial l ----
    const int quad = lane >> 4;
    unsigned short* ob = opart + (size_t)(split * BB + b) * NN * CP;
#pragma unroll
    for (int ms = 0; ms < 2; ++ms)
#pragma unroll
        for (int s8 = 0; s8 < 8; ++s8)
#pragma unroll
            for (int r = 0; r < 4; ++r)
                ob[(size_t)(m0 + ms * 16 + quad * 4 + r) * CP + s8 * 16 + col] = f2bf(oacc[ms][s8][r]);
#pragma unroll
    for (int ms = 0; ms < 2; ++ms) {
        float v = lsum[ms];
        v += __shfl_xor(v, 16);
        v += __shfl_xor(v, 32);
        if (lane < 16)
            ml[(size_t)(split * BB + b) * NN + m0 + ms * 16 + lane] = v;
    }
}

// ---------------------------------------------------------------------------
// Linear combine of 4 split partials + normalize + gamma*E + x; LDS transpose
// for contiguous [b][c][m] writes.
// ---------------------------------------------------------------------------
__global__ __launch_bounds__(256) void combine_kernel(const unsigned short* __restrict__ opart,
                                                      const float* __restrict__ ml,
                                                      const float* __restrict__ x,
                                                      const float* __restrict__ gamma,
                                                      float* __restrict__ out) {
    __shared__ float es[32 * 133];
    __shared__ float Lsh[32];
    const int t = threadIdx.x;
    const int b = blockIdx.y;
    const int m0 = blockIdx.x * 32;
    if (t < 32) {
        float L = 0.f;
#pragma unroll
        for (int s = 0; s < NSPLIT; ++s) L += ml[(size_t)(s * BB + b) * NN + m0 + t];
        Lsh[t] = gamma[0] / L;
    }
    const int tc = t & 31, tm = t >> 5;
    float acc[4][4];
#pragma unroll
    for (int i = 0; i < 4; ++i)
#pragma unroll
        for (int j = 0; j < 4; ++j) acc[i][j] = 0.f;
    for (int s = 0; s < NSPLIT; ++s) {
        const unsigned short* obp = opart + ((size_t)(s * BB + b) * NN + m0 + tm * 4) * CP + tc * 4;
#pragma unroll
        for (int i = 0; i < 4; ++i) {
            short4v v = *(const short4v*)(obp + (size_t)i * CP);
            acc[i][0] += bf2f((unsigned short)v[0]);
            acc[i][1] += bf2f((unsigned short)v[1]);
            acc[i][2] += bf2f((unsigned short)v[2]);
            acc[i][3] += bf2f((unsigned short)v[3]);
        }
    }
#pragma unroll
    for (int i = 0; i < 4; ++i)
#pragma unroll
        for (int j = 0; j < 4; ++j) es[(tm * 4 + i) * 133 + tc * 4 + j] = acc[i][j];
    __syncthreads();
    const int wave = t >> 6, lane = t & 63;
    const int half = lane >> 5, lm = lane & 31;
#pragma unroll
    for (int p = 0; p < 16; ++p) {
        int c = p * 8 + wave * 2 + half;
        if (c < CC) {
            size_t base = ((size_t)b * CC + c) * NN + m0 + lm;
            out[base] = es[lm * 133 + c] * Lsh[lm] + x[base];
        }
    }
}

extern "C" void kernel_launch(void* const* d_in, const int* in_sizes, int n_in,
                              void* d_out, int out_size, void* d_ws, size_t ws_size,
                              hipStream_t stream) {
    const float* x = (const float*)d_in[0];
    const float* Wb = (const float*)d_in[1];
    const float* gamma = (const float*)d_in[2];
    float* out = (float*)d_out;

    const size_t kfrag_b = (size_t)BB * NGRP * 4 * 64 * 8 * sizeof(unsigned short);   // 4 MB
    const size_t vfrag_b = (size_t)BB * NGRP * 8 * 64 * 4 * sizeof(unsigned short);   // 4 MB
    const size_t m2_b = (size_t)BB * NN * sizeof(float);                               // 64 KB
    const size_t ml_b = (size_t)NSPLIT * BB * NN * sizeof(float);                      // 256 KB
    const size_t opart_b = (size_t)NSPLIT * BB * NN * CP * sizeof(unsigned short);     // 16 MB
    if (ws_size < kfrag_b + vfrag_b + m2_b + ml_b + opart_b) return;

    char* w = (char*)d_ws;
    unsigned short* kfrag = (unsigned short*)w;
    unsigned short* vfrag = (unsigned short*)(w + kfrag_b);
    float* m2 = (float*)(w + kfrag_b + vfrag_b);
    float* ml = (float*)(w + kfrag_b + vfrag_b + m2_b);
    unsigned short* opart = (unsigned short*)(w + kfrag_b + vfrag_b + m2_b + ml_b);

    bf_proj_kernel<<<dim3(NN / 64, BB), 256, 0, stream>>>(x, Wb, kfrag, vfrag, m2);
    attn_kernel<<<dim3(512), 256, 0, stream>>>(kfrag, vfrag, m2, opart, ml);
    combine_kernel<<<dim3(NN / 32, BB), 256, 0, stream>>>(opart, ml, x, gamma, out);
}